// Round 2
// baseline (1704.921 us; speedup 1.0000x reference)
//
#include <hip/hip_runtime.h>

#define BLK 256

typedef __bf16 bf16;
typedef __bf16 bf16x8 __attribute__((ext_vector_type(8)));
typedef float f32x4 __attribute__((ext_vector_type(4)));

__device__ __forceinline__ float sigm(float x) { return 1.f / (1.f + __expf(-x)); }
__device__ __forceinline__ float tanh_(float x) {
    x = fminf(fmaxf(x, -15.f), 15.f);
    float e = __expf(2.f * x);
    return (e - 1.f) / (e + 1.f);
}

// async 16B global->LDS; lds dest is wave-uniform base (+ lane*16 implicit)
__device__ __forceinline__ void gl2lds(const bf16* g, bf16* l) {
    __builtin_amdgcn_global_load_lds((const __attribute__((address_space(1))) void*)g,
                                     (__attribute__((address_space(3))) void*)l, 16, 0, 0);
}

// ---------------- fused prep: tiled transposes + casts + bz ----------------
__global__ __launch_bounds__(256) void k_prep(
    const float* __restrict__ src, const float* __restrict__ tgt,
    const float* __restrict__ WH, const float* __restrict__ bH,
    const float* __restrict__ Wk, const float* __restrict__ Wr,
    const float* __restrict__ bl,
    bf16* __restrict__ srcb, bf16* __restrict__ tgtb,
    bf16* __restrict__ WHhi, bf16* __restrict__ WHlo,
    bf16* __restrict__ Wrhi, bf16* __restrict__ Wrlo,
    bf16* __restrict__ P2, float* __restrict__ bz) {
    __shared__ float tile[64][65];
    const int bid = blockIdx.x, t = threadIdx.x;
    if (bid < 512) {
        const float* in = (bid < 256) ? Wr : Wk;
        bf16* ohi = (bid < 256) ? Wrhi : P2;
        bf16* olo = (bid < 256) ? Wrlo : nullptr;
        const int b = bid & 255;
        const int tr = b >> 5, tc = b & 31;  // 8 k-blocks x 32 c-blocks of 64x64
#pragma unroll
        for (int q = 0; q < 16; q++) {
            int idx = q * 256 + t, lr = idx >> 6, lc = idx & 63;
            tile[lr][lc] = in[(size_t)(tr * 64 + lr) * 2048 + tc * 64 + lc];
        }
        __syncthreads();
#pragma unroll
        for (int q = 0; q < 16; q++) {
            int idx = q * 256 + t, lr = idx >> 6, lc = idx & 63;
            float v = tile[lc][lr];
            size_t o = (size_t)(tc * 64 + lr) * 512 + tr * 64 + lc;
            bf16 h = (bf16)v;
            ohi[o] = h;
            if (olo) olo[o] = (bf16)(v - (float)h);
        }
    } else if (bid < 520) {
        int c = (bid - 512) * 256 + t;
        float s = bl[c];
        for (int k = 0; k < 512; k++) s += bH[k] * Wr[(size_t)k * 2048 + c];
        bz[c] = s;
    } else {
        const int gt = (bid - 520) * 256 + t, NT = 504 * 256;
        for (int id = gt; id < 1048576; id += NT) srcb[id] = (bf16)src[id];
        for (int id = gt; id < 1048576; id += NT) tgtb[id] = (bf16)tgt[id];
        for (int id = gt; id < 524288; id += NT) {
            float v = WH[id];
            bf16 h = (bf16)v;
            WHhi[id] = h;
            WHlo[id] = (bf16)(v - (float)h);
        }
    }
}

// ---------------- P-matrix builder GEMM (grid 256) ----------------
// P3 = WHW_t^T, P4 = WHW_s^T (k_diag adds Wk^T=P2 itself).
__global__ __launch_bounds__(256, 4) void k_gemmP(
    const bf16* __restrict__ Wrhi, const bf16* __restrict__ Wrlo,
    const bf16* __restrict__ WHhi, const bf16* __restrict__ WHlo,
    bf16* __restrict__ P3, bf16* __restrict__ P4) {
    __shared__ __align__(16) bf16 At[64 * 64];
    __shared__ __align__(16) bf16 Bt[128 * 64];
    const int t = threadIdx.x, w = t >> 6, l = t & 63;
    const int m0 = (blockIdx.x >> 3) * 64, n0 = (blockIdx.x & 7) * 128;
    f32x4 acc[2][4] = {};
    const bf16* Aps[3] = {Wrhi, Wrlo, Wrhi};
    const bf16* Bps[3] = {WHhi, WHhi, WHlo};
    for (int ph = 0; ph < 3; ph++) {
        const bf16* Ap = Aps[ph] + (size_t)m0 * 512;
        const bf16* Bp = Bps[ph] + (size_t)n0 * 512;
        for (int kt = 0; kt < 8; kt++) {
            int k0 = kt * 64;
            __syncthreads();
#pragma unroll
            for (int q = 0; q < 2; q++) {
                int pp = q * 256 + t;
                int r = pp >> 3, c = (pp & 7) ^ (r & 7);
                gl2lds(Ap + (size_t)r * 512 + k0 + c * 8, &At[(q * 256 + w * 64) * 8]);
            }
#pragma unroll
            for (int q = 0; q < 4; q++) {
                int pp = q * 256 + t;
                int r = pp >> 3, c = (pp & 7) ^ (r & 7);
                gl2lds(Bp + (size_t)r * 512 + k0 + c * 8, &Bt[(q * 256 + w * 64) * 8]);
            }
            __syncthreads();
#pragma unroll
            for (int ks = 0; ks < 2; ks++) {
                int c = ks * 4 + (l >> 4);
                bf16x8 af[2], bb[4];
#pragma unroll
                for (int mt = 0; mt < 2; mt++) {
                    int r = (w >> 1) * 32 + mt * 16 + (l & 15);
                    af[mt] = *(const bf16x8*)&At[(r * 8 + (c ^ (r & 7))) * 8];
                }
#pragma unroll
                for (int g = 0; g < 4; g++) {
                    int r = g * 32 + (w & 1) * 16 + (l & 15);
                    bb[g] = *(const bf16x8*)&Bt[(r * 8 + (c ^ (r & 7))) * 8];
                }
#pragma unroll
                for (int mt = 0; mt < 2; mt++)
#pragma unroll
                    for (int g = 0; g < 4; g++)
                        acc[mt][g] = __builtin_amdgcn_mfma_f32_16x16x32_bf16(
                            af[mt], bb[g], acc[mt][g], 0, 0, 0);
            }
        }
    }
    const bool hihalf = (n0 >= 512);
#pragma unroll
    for (int mt = 0; mt < 2; mt++) {
#pragma unroll
        for (int g = 0; g < 4; g++) {
            int np = n0 + g * 32 + (w & 1) * 16 + (l & 15);
#pragma unroll
            for (int r = 0; r < 4; r++) {
                int c = m0 + (w >> 1) * 32 + mt * 16 + ((l >> 4) << 2) + r;
                float v = acc[mt][g][r];
                if (!hihalf) P4[(size_t)c * 512 + np] = (bf16)v;
                else P3[(size_t)c * 512 + (np - 512)] = (bf16)v;
            }
        }
    }
}

// ---------------- per-diagonal CELL-PAIR + double-buffered pipeline ----------------
// 512 threads = 2 wave-quads; quad q handles cell pair*2+q with the proven
// k_diag4 4-wave layout. B tiles (P2/P4/P3, 48 KB per K-tile) staged ONCE and
// shared by both quads -> per-cell staged bytes 8 MB -> 5 MB. LDS fully
// double-buffered (2 x 80 KB = 160 KB, 1 block/CU): STAGE(kt+1) issued BEFORE
// COMPUTE(kt) so global_load_lds flight hides under MFMA (T3 2-phase recipe).
__global__ __launch_bounds__(512, 2) void k_diag5(
    int d, int i_lo, int Kd,
    const bf16* __restrict__ srcb, const bf16* __restrict__ tgtb,
    const bf16* __restrict__ P2, const bf16* __restrict__ P3,
    const bf16* __restrict__ P4,
    const float* __restrict__ bz,
    const bf16* __restrict__ shR, bf16* __restrict__ shW,
    const bf16* __restrict__ thR, bf16* __restrict__ thW,
    float* __restrict__ sc, float* __restrict__ tc,
    float* __restrict__ out) {
    // [buf][tile 4][64x64] : As0 At0 As1 At1, 32 KB per buf
    __shared__ __align__(16) bf16 AL[2][4 * 4096];
    // [buf][mat 3][128x64] : Bk Bs Bt, 48 KB per buf
    __shared__ __align__(16) bf16 BL[2][3 * 8192];
    const int t = threadIdx.x, w = t >> 6, l = t & 63;
    const int q = w >> 2, ww = w & 3;  // quad = cell slot, ww = role within quad
    const int pair = blockIdx.x >> 4, ch0 = (blockIdx.x & 15) << 5;
    const int cell0 = pair * 2;
    const bool valid = (cell0 + q) < Kd;
    const int myCell = valid ? cell0 + q : cell0;
    const int i = i_lo + myCell, j = d - i;
    const bool uS = (j > 0), uT = (i > 0);
    const size_t stI = (size_t)i * 32768, stJ = (size_t)j * 32768;

    const int c1 = (cell0 + 1 < Kd) ? cell0 + 1 : cell0;
    const int i0 = i_lo + cell0, j0 = d - i0;
    const int i1 = i_lo + c1, j1 = d - i1;
    const bf16* A0s = (j0 == 0 ? srcb : shR) + (size_t)i0 * 32768;
    const bf16* A0t = (i0 == 0 ? tgtb : thR) + (size_t)j0 * 32768;
    const bf16* A1s = (j1 == 0 ? srcb : shR) + (size_t)i1 * 32768;
    const bf16* A1t = (i1 == 0 ? tgtb : thR) + (size_t)j1 * 32768;

    f32x4 accS[2][4] = {};  // step @ Wk  (own cell)
    f32x4 accT[2][4] = {};  // t_step @ Wk
    f32x4 accU[2][4] = {};  // shared hmid@Wr part

    auto STAGE = [&](int bf, int k0) {
        bf16* Ab = &AL[bf][0];
        {
            int r = t >> 3, c = (t & 7) ^ (r & 7);
            size_t so = (size_t)r * 512 + k0 + c * 8;
            gl2lds(A0s + so, Ab + (0 * 512 + w * 64) * 8);
            gl2lds(A0t + so, Ab + (1 * 512 + w * 64) * 8);
            gl2lds(A1s + so, Ab + (2 * 512 + w * 64) * 8);
            gl2lds(A1t + so, Ab + (3 * 512 + w * 64) * 8);
        }
        bf16* Bb = &BL[bf][0];
#pragma unroll
        for (int qq = 0; qq < 6; qq++) {
            int pp = (qq & 1) * 512 + t;
            int r = pp >> 3, c = (pp & 7) ^ (r & 7);
            size_t grow = (size_t)((r >> 5) * 512 + ch0 + (r & 31));
            const bf16* M = (qq < 2) ? P2 : (qq < 4) ? P4 : P3;
            gl2lds(M + grow * 512 + k0 + c * 8, Bb + (qq * 512 + w * 64) * 8);
        }
    };

    auto COMPUTE = [&](int bf) {
        const bf16* Ab = &AL[bf][0];
        const bf16* Bb = &BL[bf][0];
#pragma unroll
        for (int ks = 0; ks < 2; ks++) {
            int cq = ks * 4 + (l >> 4);
            bf16x8 aS[2], aT[2], bb[4];
#pragma unroll
            for (int mt = 0; mt < 2; mt++) {
                int r = (ww >> 1) * 32 + mt * 16 + (l & 15);
                int co = (r * 8 + (cq ^ (r & 7))) * 8;
                aS[mt] = *(const bf16x8*)&Ab[(q * 2) * 4096 + co];
                aT[mt] = *(const bf16x8*)&Ab[(q * 2 + 1) * 4096 + co];
            }
#pragma unroll
            for (int g = 0; g < 4; g++) {
                int r = g * 32 + (ww & 1) * 16 + (l & 15);
                bb[g] = *(const bf16x8*)&Bb[(r * 8 + (cq ^ (r & 7))) * 8];
            }
#pragma unroll
            for (int mt = 0; mt < 2; mt++)
#pragma unroll
                for (int g = 0; g < 4; g++) {
                    accS[mt][g] = __builtin_amdgcn_mfma_f32_16x16x32_bf16(
                        aS[mt], bb[g], accS[mt][g], 0, 0, 0);
                    accT[mt][g] = __builtin_amdgcn_mfma_f32_16x16x32_bf16(
                        aT[mt], bb[g], accT[mt][g], 0, 0, 0);
                }
            if (uS) {
#pragma unroll
                for (int g = 0; g < 4; g++) {
                    int r = g * 32 + (ww & 1) * 16 + (l & 15);
                    bb[g] = *(const bf16x8*)&Bb[8192 + (r * 8 + (cq ^ (r & 7))) * 8];
                }
#pragma unroll
                for (int mt = 0; mt < 2; mt++)
#pragma unroll
                    for (int g = 0; g < 4; g++)
                        accU[mt][g] = __builtin_amdgcn_mfma_f32_16x16x32_bf16(
                            aS[mt], bb[g], accU[mt][g], 0, 0, 0);
            }
            if (uT) {
#pragma unroll
                for (int g = 0; g < 4; g++) {
                    int r = g * 32 + (ww & 1) * 16 + (l & 15);
                    bb[g] = *(const bf16x8*)&Bb[16384 + (r * 8 + (cq ^ (r & 7))) * 8];
                }
#pragma unroll
                for (int mt = 0; mt < 2; mt++)
#pragma unroll
                    for (int g = 0; g < 4; g++)
                        accU[mt][g] = __builtin_amdgcn_mfma_f32_16x16x32_bf16(
                            aT[mt], bb[g], accU[mt][g], 0, 0, 0);
            }
        }
    };

    STAGE(0, 0);
    __syncthreads();  // compiler drains vmcnt(0) before the barrier
    int bf = 0;
#pragma unroll 1
    for (int kt = 0; kt < 8; kt++) {
        if (kt < 7) STAGE(bf ^ 1, (kt + 1) * 64);  // in flight during compute
        COMPUTE(bf);
        __syncthreads();  // drain: next buf ready, everyone done reading cur
        bf ^= 1;
    }

    if (!valid) return;  // tail quad: duplicate compute, no writes

    // in-register gate epilogue for BOTH sides of this quad's cell
    const int h = ch0 + (ww & 1) * 16 + (l & 15);
    float bzv[4];
#pragma unroll
    for (int g = 0; g < 4; g++) bzv[g] = bz[g * 512 + h];
#pragma unroll
    for (int mt = 0; mt < 2; mt++) {
#pragma unroll
        for (int r = 0; r < 4; r++) {
            int b = (ww >> 1) * 32 + mt * 16 + ((l >> 4) << 2) + r;
            float u0 = accU[mt][0][r], u1 = accU[mt][1][r];
            float u2 = accU[mt][2][r], u3 = accU[mt][3][r];
            {  // side 0: z_s
                float zi = accS[mt][0][r] + u0 + bzv[0];
                float zf = accS[mt][1][r] + u1 + bzv[1];
                float zg = accS[mt][2][r] + u2 + bzv[2];
                float zo = accS[mt][3][r] + u3 + bzv[3];
                size_t off = stI + (size_t)b * 512 + h;
                float cold = uS ? sc[off] : 0.f;
                float c2 = sigm(zf) * cold + sigm(zi) * tanh_(zg);
                float h2 = sigm(zo) * tanh_(c2);
                sc[off] = c2;
                shW[off] = (bf16)h2;
                if (j == 31) out[off] = h2;  // source_out[i]
            }
            {  // side 1: z_t
                float zi = accT[mt][0][r] + u0 + bzv[0];
                float zf = accT[mt][1][r] + u1 + bzv[1];
                float zg = accT[mt][2][r] + u2 + bzv[2];
                float zo = accT[mt][3][r] + u3 + bzv[3];
                size_t off = stJ + (size_t)b * 512 + h;
                float cold = uT ? tc[off] : 0.f;
                float c2 = sigm(zf) * cold + sigm(zi) * tanh_(zg);
                float h2 = sigm(zo) * tanh_(c2);
                tc[off] = c2;
                thW[off] = (bf16)h2;
                if (i == 31) out[1048576 + off] = h2;  // t_final[0][j]
            }
        }
    }
}

// ---------------- host ----------------

extern "C" void kernel_launch(void* const* d_in, const int* in_sizes, int n_in,
                              void* d_out, int out_size, void* d_ws, size_t ws_size,
                              hipStream_t stream) {
    char* w = (char*)d_ws;
    const size_t MB = 1u << 20;
    const float* src = (const float*)d_in[0];
    const float* tgt = (const float*)d_in[1];
    const float* WH = (const float*)d_in[2];
    const float* bH = (const float*)d_in[3];
    const float* Wk = (const float*)d_in[4];
    const float* Wr = (const float*)d_in[5];
    const float* bl = (const float*)d_in[6];
    float* out = (float*)d_out;

    bf16* srcb = (bf16*)(w + 0 * MB);    // [32][64][512]
    bf16* tgtb = (bf16*)(w + 2 * MB);
    bf16* WHhi = (bf16*)(w + 4 * MB);    // [1024][512]
    bf16* WHlo = (bf16*)(w + 5 * MB);
    bf16* Wrhi = (bf16*)(w + 6 * MB);    // [2048][512] (W_rec^T)
    bf16* Wrlo = (bf16*)(w + 8 * MB);
    bf16* P2 = (bf16*)(w + 12 * MB);     // Wk^T
    bf16* P3 = (bf16*)(w + 14 * MB);     // WHW_t^T
    bf16* P4 = (bf16*)(w + 16 * MB);     // WHW_s^T
    float* bz = (float*)(w + 20 * MB);   // [2048]
    bf16* sh = (bf16*)(w + 21 * MB);     // [2][32][64][512] double-buffered
    bf16* th = (bf16*)(w + 25 * MB);
    float* sc = (float*)(w + 29 * MB);   // [32][64][512] fp32
    float* tc = (float*)(w + 33 * MB);   // end: 37 MB

    k_prep<<<1024, BLK, 0, stream>>>(src, tgt, WH, bH, Wk, Wr, bl, srcb, tgtb,
                                     WHhi, WHlo, Wrhi, Wrlo, P2, bz);
    k_gemmP<<<256, BLK, 0, stream>>>(Wrhi, Wrlo, WHhi, WHlo, P3, P4);

    for (int d = 0; d < 63; d++) {
        int i_lo = d > 31 ? d - 31 : 0;
        int i_hi = d < 31 ? d : 31;
        int Kd = i_hi - i_lo + 1;
        int nPairs = (Kd + 1) >> 1;
        const bf16* shR = sh + (size_t)(d & 1) * 1048576;
        bf16* shW = sh + (size_t)((d + 1) & 1) * 1048576;
        const bf16* thR = th + (size_t)(d & 1) * 1048576;
        bf16* thW = th + (size_t)((d + 1) & 1) * 1048576;
        k_diag5<<<nPairs * 16, 512, 0, stream>>>(d, i_lo, Kd, srcb, tgtb, P2, P3, P4,
                                                 bz, shR, shW, thR, thW, sc, tc, out);
    }
}

// Round 3
// 1424.954 us; speedup vs baseline: 1.1965x; 1.1965x over previous
//
#include <hip/hip_runtime.h>

#define BLK 256

typedef __bf16 bf16;
typedef __bf16 bf16x8 __attribute__((ext_vector_type(8)));
typedef float f32x4 __attribute__((ext_vector_type(4)));

__device__ __forceinline__ float sigm(float x) { return 1.f / (1.f + __expf(-x)); }
__device__ __forceinline__ float tanh_(float x) {
    x = fminf(fmaxf(x, -15.f), 15.f);
    float e = __expf(2.f * x);
    return (e - 1.f) / (e + 1.f);
}

// async 16B global->LDS; lds dest is wave-uniform base (+ lane*16 implicit)
__device__ __forceinline__ void gl2lds(const bf16* g, bf16* l) {
    __builtin_amdgcn_global_load_lds((const __attribute__((address_space(1))) void*)g,
                                     (__attribute__((address_space(3))) void*)l, 16, 0, 0);
}

// ---------------- fused prep: tiled transposes + casts + bz ----------------
__global__ __launch_bounds__(256) void k_prep(
    const float* __restrict__ src, const float* __restrict__ tgt,
    const float* __restrict__ WH, const float* __restrict__ bH,
    const float* __restrict__ Wk, const float* __restrict__ Wr,
    const float* __restrict__ bl,
    bf16* __restrict__ srcb, bf16* __restrict__ tgtb,
    bf16* __restrict__ WHhi, bf16* __restrict__ WHlo,
    bf16* __restrict__ Wrhi, bf16* __restrict__ Wrlo,
    bf16* __restrict__ P2, float* __restrict__ bz) {
    __shared__ float tile[64][65];
    const int bid = blockIdx.x, t = threadIdx.x;
    if (bid < 512) {
        const float* in = (bid < 256) ? Wr : Wk;
        bf16* ohi = (bid < 256) ? Wrhi : P2;
        bf16* olo = (bid < 256) ? Wrlo : nullptr;
        const int b = bid & 255;
        const int tr = b >> 5, tc = b & 31;  // 8 k-blocks x 32 c-blocks of 64x64
#pragma unroll
        for (int q = 0; q < 16; q++) {
            int idx = q * 256 + t, lr = idx >> 6, lc = idx & 63;
            tile[lr][lc] = in[(size_t)(tr * 64 + lr) * 2048 + tc * 64 + lc];
        }
        __syncthreads();
#pragma unroll
        for (int q = 0; q < 16; q++) {
            int idx = q * 256 + t, lr = idx >> 6, lc = idx & 63;
            float v = tile[lc][lr];
            size_t o = (size_t)(tc * 64 + lr) * 512 + tr * 64 + lc;
            bf16 h = (bf16)v;
            ohi[o] = h;
            if (olo) olo[o] = (bf16)(v - (float)h);
        }
    } else if (bid < 520) {
        int c = (bid - 512) * 256 + t;
        float s = bl[c];
        for (int k = 0; k < 512; k++) s += bH[k] * Wr[(size_t)k * 2048 + c];
        bz[c] = s;
    } else {
        const int gt = (bid - 520) * 256 + t, NT = 504 * 256;
        for (int id = gt; id < 1048576; id += NT) srcb[id] = (bf16)src[id];
        for (int id = gt; id < 1048576; id += NT) tgtb[id] = (bf16)tgt[id];
        for (int id = gt; id < 524288; id += NT) {
            float v = WH[id];
            bf16 h = (bf16)v;
            WHhi[id] = h;
            WHlo[id] = (bf16)(v - (float)h);
        }
    }
}

// ---------------- P-matrix builder GEMM (R4/R6-proven body, grid 256) ----------------
__global__ __launch_bounds__(256, 4) void k_gemmP(
    const bf16* __restrict__ Wrhi, const bf16* __restrict__ Wrlo,
    const bf16* __restrict__ WHhi, const bf16* __restrict__ WHlo,
    const float* __restrict__ Wk,
    bf16* __restrict__ P1, bf16* __restrict__ P3,
    bf16* __restrict__ P4, bf16* __restrict__ P5) {
    __shared__ __align__(16) bf16 At[64 * 64];
    __shared__ __align__(16) bf16 Bt[128 * 64];
    const int t = threadIdx.x, w = t >> 6, l = t & 63;
    const int m0 = (blockIdx.x >> 3) * 64, n0 = (blockIdx.x & 7) * 128;
    f32x4 acc[2][4] = {};
    const bf16* Aps[3] = {Wrhi, Wrlo, Wrhi};
    const bf16* Bps[3] = {WHhi, WHhi, WHlo};
    for (int ph = 0; ph < 3; ph++) {
        const bf16* Ap = Aps[ph] + (size_t)m0 * 512;
        const bf16* Bp = Bps[ph] + (size_t)n0 * 512;
        for (int kt = 0; kt < 8; kt++) {
            int k0 = kt * 64;
            __syncthreads();
#pragma unroll
            for (int q = 0; q < 2; q++) {
                int pp = q * 256 + t;
                int r = pp >> 3, c = (pp & 7) ^ (r & 7);
                gl2lds(Ap + (size_t)r * 512 + k0 + c * 8, &At[(q * 256 + w * 64) * 8]);
            }
#pragma unroll
            for (int q = 0; q < 4; q++) {
                int pp = q * 256 + t;
                int r = pp >> 3, c = (pp & 7) ^ (r & 7);
                gl2lds(Bp + (size_t)r * 512 + k0 + c * 8, &Bt[(q * 256 + w * 64) * 8]);
            }
            __syncthreads();
#pragma unroll
            for (int ks = 0; ks < 2; ks++) {
                int c = ks * 4 + (l >> 4);
                bf16x8 af[2], bb[4];
#pragma unroll
                for (int mt = 0; mt < 2; mt++) {
                    int r = (w >> 1) * 32 + mt * 16 + (l & 15);
                    af[mt] = *(const bf16x8*)&At[(r * 8 + (c ^ (r & 7))) * 8];
                }
#pragma unroll
                for (int g = 0; g < 4; g++) {
                    int r = g * 32 + (w & 1) * 16 + (l & 15);
                    bb[g] = *(const bf16x8*)&Bt[(r * 8 + (c ^ (r & 7))) * 8];
                }
#pragma unroll
                for (int mt = 0; mt < 2; mt++)
#pragma unroll
                    for (int g = 0; g < 4; g++)
                        acc[mt][g] = __builtin_amdgcn_mfma_f32_16x16x32_bf16(
                            af[mt], bb[g], acc[mt][g], 0, 0, 0);
            }
        }
    }
    const bool hihalf = (n0 >= 512);
#pragma unroll
    for (int mt = 0; mt < 2; mt++) {
#pragma unroll
        for (int g = 0; g < 4; g++) {
            int np = n0 + g * 32 + (w & 1) * 16 + (l & 15);
#pragma unroll
            for (int r = 0; r < 4; r++) {
                int c = m0 + (w >> 1) * 32 + mt * 16 + ((l >> 4) << 2) + r;
                float v = acc[mt][g][r];
                if (!hihalf) {
                    P4[(size_t)c * 512 + np] = (bf16)v;
                    P1[(size_t)c * 512 + np] = (bf16)(v + Wk[(size_t)np * 2048 + c]);
                } else {
                    int kk = np - 512;
                    P3[(size_t)c * 512 + kk] = (bf16)v;
                    P5[(size_t)c * 512 + kk] = (bf16)(v + Wk[(size_t)kk * 2048 + c]);
                }
            }
        }
    }
}

// ---------------- per-diagonal fused GEMM + LSTM gates, K-tile=64 ----------------
// Identical math/layout to the proven 1409.7us k_diag3, with BK halved 128->64:
// LDS 24 KB (A 64x64 + B 128x64, k_gemmP's proven staging pattern) so 4-6
// blocks/CU fit (vs 3). Evidence R0/R1: this kernel is latency-bound and
// inter-block overlap is the only effective hiding mechanism; fat diagonal
// (1024 blocks) now fits in ONE residency wave at 4/CU.
__global__ __launch_bounds__(256, 4) void k_diag6(
    int d, int i_lo,
    const bf16* __restrict__ srcb, const bf16* __restrict__ tgtb,
    const bf16* __restrict__ P1, const bf16* __restrict__ P2,
    const bf16* __restrict__ P3, const bf16* __restrict__ P4,
    const bf16* __restrict__ P5,
    const float* __restrict__ bz,
    const bf16* __restrict__ shR, bf16* __restrict__ shW,
    const bf16* __restrict__ thR, bf16* __restrict__ thW,
    float* __restrict__ sc, float* __restrict__ tc,
    float* __restrict__ out) {
    __shared__ __align__(16) bf16 At[64 * 64];   //  8 KB
    __shared__ __align__(16) bf16 Bt[128 * 64];  // 16 KB
    const int t = threadIdx.x, w = t >> 6, l = t & 63;
    const int cell = blockIdx.x >> 5, sub = blockIdx.x & 31;
    const int side = sub >> 4, ch0 = (sub & 15) << 5;
    const int i = i_lo + cell, j = d - i;
    const size_t stI = (size_t)i * 32768, stJ = (size_t)j * 32768;

    const bf16* Ah[2];
    const bf16* Wh[2];
    int nh = 0;
    if (side == 0) {  // z_s
        Ah[nh] = (j == 0 ? srcb : shR) + stI;
        Wh[nh] = (j == 0 ? P2 : P1);
        nh++;
        if (i > 0) { Ah[nh] = thR + stJ; Wh[nh] = P3; nh++; }
    } else {  // z_t
        if (j > 0) { Ah[nh] = shR + stI; Wh[nh] = P4; nh++; }
        Ah[nh] = (i == 0 ? tgtb : thR) + stJ;
        Wh[nh] = (i == 0 ? P2 : P5);
        nh++;
    }

    f32x4 acc[2][4] = {};
    for (int hh = 0; hh < nh; hh++) {
        const bf16* Ap = Ah[hh];
        const bf16* Wp = Wh[hh];
#pragma unroll 1
        for (int kt = 0; kt < 8; kt++) {
            int k0 = kt * 64;
            __syncthreads();
            // A tile: 64 rows x 8 chunks = 512 chunks, 2 issues
#pragma unroll
            for (int q = 0; q < 2; q++) {
                int pp = q * 256 + t;
                int r = pp >> 3, c = (pp & 7) ^ (r & 7);
                gl2lds(Ap + (size_t)r * 512 + k0 + c * 8, &At[(q * 256 + w * 64) * 8]);
            }
            // B tile: 128 rows (4 gates x 32 h) x 8 chunks = 1024 chunks, 4 issues
#pragma unroll
            for (int q = 0; q < 4; q++) {
                int pp = q * 256 + t;
                int r = pp >> 3, c = (pp & 7) ^ (r & 7);
                size_t grow = (size_t)((r >> 5) * 512 + ch0 + (r & 31));
                gl2lds(Wp + grow * 512 + k0 + c * 8, &Bt[(q * 256 + w * 64) * 8]);
            }
            __syncthreads();
#pragma unroll
            for (int ks = 0; ks < 2; ks++) {
                int cq = ks * 4 + (l >> 4);
                bf16x8 af[2], bb[4];
#pragma unroll
                for (int mt = 0; mt < 2; mt++) {
                    int r = (w >> 1) * 32 + mt * 16 + (l & 15);
                    af[mt] = *(const bf16x8*)&At[(r * 8 + (cq ^ (r & 7))) * 8];
                }
#pragma unroll
                for (int g = 0; g < 4; g++) {
                    int r = g * 32 + (w & 1) * 16 + (l & 15);
                    bb[g] = *(const bf16x8*)&Bt[(r * 8 + (cq ^ (r & 7))) * 8];
                }
#pragma unroll
                for (int mt = 0; mt < 2; mt++)
#pragma unroll
                    for (int g = 0; g < 4; g++)
                        acc[mt][g] = __builtin_amdgcn_mfma_f32_16x16x32_bf16(
                            af[mt], bb[g], acc[mt][g], 0, 0, 0);
            }
        }
    }

    // in-register gate epilogue: lane holds all 4 gates of its (b, h)
    const int h = ch0 + (w & 1) * 16 + (l & 15);
    float bzv[4];
#pragma unroll
    for (int g = 0; g < 4; g++) bzv[g] = bz[g * 512 + h];
#pragma unroll
    for (int mt = 0; mt < 2; mt++) {
#pragma unroll
        for (int r = 0; r < 4; r++) {
            int b = (w >> 1) * 32 + mt * 16 + ((l >> 4) << 2) + r;
            float zi = acc[mt][0][r] + bzv[0];
            float zf = acc[mt][1][r] + bzv[1];
            float zg = acc[mt][2][r] + bzv[2];
            float zo = acc[mt][3][r] + bzv[3];
            if (side == 0) {
                size_t off = stI + (size_t)b * 512 + h;
                float cold = (j == 0) ? 0.f : sc[off];
                float c2 = sigm(zf) * cold + sigm(zi) * tanh_(zg);
                float h2 = sigm(zo) * tanh_(c2);
                sc[off] = c2;
                shW[off] = (bf16)h2;
                if (j == 31) out[off] = h2;  // source_out[i]
            } else {
                size_t off = stJ + (size_t)b * 512 + h;
                float cold = (i == 0) ? 0.f : tc[off];
                float c2 = sigm(zf) * cold + sigm(zi) * tanh_(zg);
                float h2 = sigm(zo) * tanh_(c2);
                tc[off] = c2;
                thW[off] = (bf16)h2;
                if (i == 31) out[1048576 + off] = h2;  // t_final[0][j]
            }
        }
    }
}

// ---------------- host ----------------

extern "C" void kernel_launch(void* const* d_in, const int* in_sizes, int n_in,
                              void* d_out, int out_size, void* d_ws, size_t ws_size,
                              hipStream_t stream) {
    char* w = (char*)d_ws;
    const size_t MB = 1u << 20;
    const float* src = (const float*)d_in[0];
    const float* tgt = (const float*)d_in[1];
    const float* WH = (const float*)d_in[2];
    const float* bH = (const float*)d_in[3];
    const float* Wk = (const float*)d_in[4];
    const float* Wr = (const float*)d_in[5];
    const float* bl = (const float*)d_in[6];
    float* out = (float*)d_out;

    bf16* srcb = (bf16*)(w + 0 * MB);    // [32][64][512]
    bf16* tgtb = (bf16*)(w + 2 * MB);
    bf16* WHhi = (bf16*)(w + 4 * MB);    // [1024][512]
    bf16* WHlo = (bf16*)(w + 5 * MB);
    bf16* Wrhi = (bf16*)(w + 6 * MB);    // [2048][512] (W_rec^T)
    bf16* Wrlo = (bf16*)(w + 8 * MB);
    bf16* P1 = (bf16*)(w + 10 * MB);     // Wk^T + WHW_hi^T
    bf16* P2 = (bf16*)(w + 12 * MB);     // Wk^T
    bf16* P3 = (bf16*)(w + 14 * MB);     // WHW_lo^T
    bf16* P4 = (bf16*)(w + 16 * MB);     // WHW_hi^T
    bf16* P5 = (bf16*)(w + 18 * MB);     // Wk^T + WHW_lo^T
    float* bz = (float*)(w + 20 * MB);   // [2048]
    bf16* sh = (bf16*)(w + 21 * MB);     // [2][32][64][512] double-buffered
    bf16* th = (bf16*)(w + 25 * MB);
    float* sc = (float*)(w + 29 * MB);   // [32][64][512] fp32
    float* tc = (float*)(w + 33 * MB);   // end: 37 MB

    k_prep<<<1024, BLK, 0, stream>>>(src, tgt, WH, bH, Wk, Wr, bl, srcb, tgtb,
                                     WHhi, WHlo, Wrhi, Wrlo, P2, bz);
    k_gemmP<<<256, BLK, 0, stream>>>(Wrhi, Wrlo, WHhi, WHlo, Wk, P1, P3, P4, P5);

    for (int d = 0; d < 63; d++) {
        int i_lo = d > 31 ? d - 31 : 0;
        int i_hi = d < 31 ? d : 31;
        int Kd = i_hi - i_lo + 1;
        const bf16* shR = sh + (size_t)(d & 1) * 1048576;
        bf16* shW = sh + (size_t)((d + 1) & 1) * 1048576;
        const bf16* thR = th + (size_t)(d & 1) * 1048576;
        bf16* thW = th + (size_t)((d + 1) & 1) * 1048576;
        k_diag6<<<Kd * 32, BLK, 0, stream>>>(d, i_lo, srcb, tgtb, P1, P2, P3, P4, P5,
                                             bz, shR, shW, thR, thW, sc, tc, out);
    }
}